// Round 11
// baseline (59.965 us; speedup 1.0000x reference)
//
#include <hip/hip_runtime.h>

#define T_LEN 65536
#define WSEG  1024      // elements per wave segment
#define CHUNK 16        // per-thread elements
#define WARM  32        // seed warm-up: rho^32 = (a2/a0)^16 ~ 5e-13, below fp32 eps
#define NT    256       // 4 waves per block
#define NWAVE 4
#define RS    17        // LDS row stride (floats): 16 + 1 -> start banks 17l mod 32, conflict-free

typedef float vfloat4 __attribute__((ext_vector_type(4)));

#define SQMAT(a00,a01,a10,a11) {                      \
    float n00=a00*a00+a01*a10, n01=a00*a01+a01*a11;   \
    float n10=a10*a00+a11*a10, n11=a10*a01+a11*a11;   \
    a00=n00; a01=n01; a10=n10; a11=n11; }

#define WAVE_FENCE() do {                                   \
    asm volatile("s_waitcnt lgkmcnt(0)" ::: "memory");      \
    __builtin_amdgcn_sched_barrier(0);                      \
    __builtin_amdgcn_wave_barrier();                        \
} while (0)

__attribute__((amdgpu_flat_work_group_size(NT, NT)))
__global__ void iir_wave_kernel(const float* __restrict__ x,
                                const float* __restrict__ bco,
                                const float* __restrict__ aco,
                                float* __restrict__ y)
{
    const int tid  = threadIdx.x;
    const int wave = tid >> 6;
    const int lane = tid & 63;
    const long segbase = (long)blockIdx.x * (NWAVE * WSEG) + (long)wave * WSEG;
    const bool rowstart = ((segbase & (T_LEN - 1)) == 0);

    const float inv_a0 = 1.0f / aco[0];
    const float b0 = bco[0]*inv_a0, b1 = bco[1]*inv_a0, b2 = bco[2]*inv_a0;
    const float c1 = aco[1]*inv_a0, c2 = aco[2]*inv_a0;

    __shared__ float tbuf[NWAVE][64 * RS];   // 17.4 KB -> 8 blocks/CU
    float* wb = tbuf[wave];

    // ---- CONTIGUOUS payload loads: 4 x 1KB per wave (copy-ubench pattern) ----
    float4 g0 = *(const float4*)(x + segbase +   0 + 4*lane);
    float4 g1 = *(const float4*)(x + segbase + 256 + 4*lane);
    float4 g2 = *(const float4*)(x + segbase + 512 + 4*lane);
    float4 g3 = *(const float4*)(x + segbase + 768 + 4*lane);

    // ---- segment seed warm-up (all lanes redundant, broadcast loads; runs
    //      while the payload loads are in flight). fm1/fm2 end as
    //      x[segbase-1], x[segbase-2] -> lane0's FIR boundary for free. ----
    float fm1 = 0.f, fm2 = 0.f;   // FIR state through segbase-1
    float t0 = 0.f, t1 = 0.f;     // IIR state (y[segbase-1], y[segbase-2])
    if (!rowstart) {
        const float4* wv = (const float4*)(x + segbase - WARM);
        float w1 = 0.f, w2 = 0.f;
        #pragma unroll
        for (int q = 0; q < WARM / 4; ++q) {
            float4 v = wv[q];
            float u0 = b0*v.x + b1*fm1 + b2*fm2;
            float u1 = b0*v.y + b1*v.x + b2*fm1;
            float u2 = b0*v.z + b1*v.y + b2*v.x;
            float u3 = b0*v.w + b1*v.z + b2*v.y;
            fm2 = v.z; fm1 = v.w;
            float y0 = u0 - c1*w1 - c2*w2;
            float y1 = u1 - c1*y0 - c2*w1;
            float y2 = u2 - c1*y1 - c2*y0;
            float y3 = u3 - c1*y2 - c2*y1;
            w2 = y2; w1 = y3;
        }
        t0 = w1; t1 = w2;
    }

    // ---- stage-in transpose: element e -> wb[(e>>4)*RS + (e&15)] ----
    {
        const int rb  = lane >> 2;        // row within 16-row group
        const int col = 4 * (lane & 3);
        *(float4*)(wb + (  0 + rb)*RS + col) = g0;
        *(float4*)(wb + ( 16 + rb)*RS + col) = g1;
        *(float4*)(wb + ( 32 + rb)*RS + col) = g2;
        *(float4*)(wb + ( 48 + rb)*RS + col) = g3;
    }
    WAVE_FENCE();

    // ---- each lane reads its contiguous 16-element chunk (conflict-free) ----
    float4 v0 = *(const float4*)(wb + lane*RS +  0);
    float4 v1 = *(const float4*)(wb + lane*RS +  4);
    float4 v2 = *(const float4*)(wb + lane*RS +  8);
    float4 v3 = *(const float4*)(wb + lane*RS + 12);

    // ---- FIR boundary: neighbor lane's last two x via shuffle ----
    float xm1 = __shfl_up(v3.w, 1, 64);
    float xm2 = __shfl_up(v3.z, 1, 64);
    if (lane == 0) { xm1 = fm1; xm2 = fm2; }   // exact (zeros at rowstart)

    // ---- FIR + zero-state pass 1 (u kept in registers) ----
    float u[CHUNK];
    float yp1 = 0.f, yp2 = 0.f;
#define STEP4(V, O)                                                  \
    {                                                                \
        float u0 = b0*(V).x + b1*xm1   + b2*xm2;                     \
        float u1 = b0*(V).y + b1*(V).x + b2*xm1;                     \
        float u2 = b0*(V).z + b1*(V).y + b2*(V).x;                   \
        float u3 = b0*(V).w + b1*(V).z + b2*(V).y;                   \
        xm2 = (V).z; xm1 = (V).w;                                    \
        u[(O)+0]=u0; u[(O)+1]=u1; u[(O)+2]=u2; u[(O)+3]=u3;          \
        float y0 = u0 - c1*yp1 - c2*yp2;                             \
        float y1 = u1 - c1*y0  - c2*yp1;                             \
        float y2 = u2 - c1*y1  - c2*y0;                              \
        float y3 = u3 - c1*y2  - c2*y1;                              \
        yp2 = y2; yp1 = y3;                                          \
    }
    STEP4(v0, 0) STEP4(v1, 4) STEP4(v2, 8) STEP4(v3, 12)
#undef STEP4
    #pragma unroll
    for (int j = 0; j < CHUNK; ++j) asm volatile("" : "+v"(u[j]));  // no remat

    // ---- intra-wave inclusive scan (shuffles); M: A^16 -> A^1024 ----
    float s0 = yp1, s1 = yp2;
    float m00 = -c1, m01 = -c2, m10 = 1.f, m11 = 0.f;
    #pragma unroll
    for (int k = 0; k < 4; ++k) SQMAT(m00,m01,m10,m11)   // A -> A^16
    #pragma unroll
    for (int k = 0; k < 6; ++k) {
        int off = 1 << k;
        float p0 = __shfl_up(s0, off, 64);
        float p1 = __shfl_up(s1, off, 64);
        if (lane < off) { p0 = 0.f; p1 = 0.f; }
        s0 += m00*p0 + m01*p1;
        s1 += m10*p0 + m11*p1;
        SQMAT(m00,m01,m10,m11)
    }

    // ---- seed transform: t = A^(16*lane) * seed ----
    {
        float e00 = -c1, e01 = -c2, e10 = 1.f, e11 = 0.f;
        #pragma unroll
        for (int k = 0; k < 4; ++k) SQMAT(e00,e01,e10,e11)
        #pragma unroll
        for (int k = 0; k < 6; ++k) {
            if (lane & (1 << k)) {
                float q0 = e00*t0 + e01*t1;
                float q1 = e10*t0 + e11*t1;
                t0 = q0; t1 = q1;
            }
            SQMAT(e00,e01,e10,e11)
        }
    }

    // exclusive within-wave part
    float ex0 = __shfl_up(s0, 1, 64);
    float ex1 = __shfl_up(s1, 1, 64);
    if (lane == 0) { ex0 = 0.f; ex1 = 0.f; }

    // ---- pass 2: true seed; y overwrites u[] ----
    yp1 = ex0 + t0;
    yp2 = ex1 + t1;
    #pragma unroll
    for (int j = 0; j < CHUNK; ++j) {
        float yj = u[j] - c1*yp1 - c2*yp2;
        yp2 = yp1; yp1 = yj;
        u[j] = yj;
    }

    // ---- stage-out into same tile, then contiguous nt sweep ----
    WAVE_FENCE();   // all chunk-reads of tbuf done before overwrite
    #pragma unroll
    for (int q = 0; q < 4; ++q)
        *(float4*)(wb + lane*RS + 4*q) = make_float4(u[4*q], u[4*q+1], u[4*q+2], u[4*q+3]);
    WAVE_FENCE();

    {
        const int rb  = lane >> 2;
        const int col = 4 * (lane & 3);
        #pragma unroll
        for (int i = 0; i < 4; ++i) {
            vfloat4 o;
            o.x = wb[(i*16 + rb)*RS + col + 0];
            o.y = wb[(i*16 + rb)*RS + col + 1];
            o.z = wb[(i*16 + rb)*RS + col + 2];
            o.w = wb[(i*16 + rb)*RS + col + 3];
            __builtin_nontemporal_store(
                o, (vfloat4*)(y + segbase + i*256 + 4*lane));
        }
    }
}

extern "C" void kernel_launch(void* const* d_in, const int* in_sizes, int n_in,
                              void* d_out, int out_size, void* d_ws, size_t ws_size,
                              hipStream_t stream) {
    const float* x = (const float*)d_in[0];
    const float* b = (const float*)d_in[1];
    const float* a = (const float*)d_in[2];
    float* y = (float*)d_out;

    const int nblocks = in_sizes[0] / (NWAVE * WSEG);   // 8192
    iir_wave_kernel<<<nblocks, NT, 0, stream>>>(x, b, a, y);
}

// Round 12
// 47.011 us; speedup vs baseline: 1.2755x; 1.2755x over previous
//
#include <hip/hip_runtime.h>

#define T_LEN 65536
#define WSEG  1024      // elements per wave segment
#define CHUNK 16        // per-thread elements
#define WARM  24        // seed warm-up: rho^24 = (a2/a0)^12 ~ 6.5e-10, below fp32 eps
#define NT    256       // 4 waves per block
#define NWAVE 4
#define TP    20        // LDS row stride (floats): 16 + 4 pad, 16B-aligned

typedef float vfloat4 __attribute__((ext_vector_type(4)));

#define SQMAT(a00,a01,a10,a11) {                      \
    float n00=a00*a00+a01*a10, n01=a00*a01+a01*a11;   \
    float n10=a10*a00+a11*a10, n11=a10*a01+a11*a11;   \
    a00=n00; a01=n01; a10=n10; a11=n11; }

__attribute__((amdgpu_flat_work_group_size(NT, NT)))
__global__ void iir_wave_kernel(const float* __restrict__ x,
                                const float* __restrict__ bco,
                                const float* __restrict__ aco,
                                float* __restrict__ y)
{
    const int tid  = threadIdx.x;
    const int wave = tid >> 6;
    const int lane = tid & 63;
    const long segbase = (long)blockIdx.x * (NWAVE * WSEG) + (long)wave * WSEG;
    const long base    = segbase + (long)lane * CHUNK;
    const bool rowstart = ((segbase & (T_LEN - 1)) == 0);

    const float inv_a0 = 1.0f / aco[0];
    const float b0 = bco[0]*inv_a0, b1 = bco[1]*inv_a0, b2 = bco[2]*inv_a0;
    const float c1 = aco[1]*inv_a0, c2 = aco[2]*inv_a0;

    __shared__ float tbuf[NWAVE][64][TP];   // 20 KB -> 8 blocks/CU

    // ---- warm-up loads FIRST (they gate pass-1 start via lane0 boundary) ----
    float4 wv0, wv1, wv2, wv3, wv4, wv5;
    if (!rowstart) {
        const float4* wv = (const float4*)(x + segbase - WARM);
        wv0 = wv[0]; wv1 = wv[1]; wv2 = wv[2];
        wv3 = wv[3]; wv4 = wv[4]; wv5 = wv[5];
    }

    // ---- payload loads: 16 floats per lane, in flight under warm-up compute ----
    const float4* xv = (const float4*)(x + base);
    float4 v0 = xv[0], v1 = xv[1], v2 = xv[2], v3 = xv[3];

    // ---- segment seed: all lanes redundantly run WARM steps (broadcast data).
    //      fm1/fm2 end as x[segbase-1], x[segbase-2] (lane0 FIR boundary);
    //      (t0,t1) = (y[segbase-1], y[segbase-2]) with ~6e-10 truncation error. ----
    float fm1 = 0.f, fm2 = 0.f;
    float t0 = 0.f, t1 = 0.f;
    if (!rowstart) {
        float w1 = 0.f, w2 = 0.f;
        float4 wvv[6] = { wv0, wv1, wv2, wv3, wv4, wv5 };
        #pragma unroll
        for (int q = 0; q < WARM / 4; ++q) {
            float4 v = wvv[q];
            float u0 = b0*v.x + b1*fm1 + b2*fm2;
            float u1 = b0*v.y + b1*v.x + b2*fm1;
            float u2 = b0*v.z + b1*v.y + b2*v.x;
            float u3 = b0*v.w + b1*v.z + b2*v.y;
            fm2 = v.z; fm1 = v.w;
            float y0 = u0 - c1*w1 - c2*w2;
            float y1 = u1 - c1*y0 - c2*w1;
            float y2 = u2 - c1*y1 - c2*y0;
            float y3 = u3 - c1*y2 - c2*y1;
            w2 = y2; w1 = y3;
        }
        t0 = w1; t1 = w2;
    }

    // ---- FIR boundary: neighbor lane's last two x via shuffle ----
    float xm1 = __shfl_up(v3.w, 1, 64);
    float xm2 = __shfl_up(v3.z, 1, 64);
    if (lane == 0) { xm1 = fm1; xm2 = fm2; }   // exact zeros at rowstart

    // ---- FIR + zero-state pass 1 (u kept in registers) ----
    float u[CHUNK];
    float yp1 = 0.f, yp2 = 0.f;
#define STEP4(V, O)                                                  \
    {                                                                \
        float u0 = b0*(V).x + b1*xm1   + b2*xm2;                     \
        float u1 = b0*(V).y + b1*(V).x + b2*xm1;                     \
        float u2 = b0*(V).z + b1*(V).y + b2*(V).x;                   \
        float u3 = b0*(V).w + b1*(V).z + b2*(V).y;                   \
        xm2 = (V).z; xm1 = (V).w;                                    \
        u[(O)+0]=u0; u[(O)+1]=u1; u[(O)+2]=u2; u[(O)+3]=u3;          \
        float y0 = u0 - c1*yp1 - c2*yp2;                             \
        float y1 = u1 - c1*y0  - c2*yp1;                             \
        float y2 = u2 - c1*y1  - c2*y0;                              \
        float y3 = u3 - c1*y2  - c2*y1;                              \
        yp2 = y2; yp1 = y3;                                          \
    }
    STEP4(v0, 0) STEP4(v1, 4) STEP4(v2, 8) STEP4(v3, 12)
#undef STEP4
    #pragma unroll
    for (int j = 0; j < CHUNK; ++j) asm volatile("" : "+v"(u[j]));  // no remat

    // ---- intra-wave inclusive scan + fused seed transform ----
    // At scan step k, m = A^(16*2^k): combine partials AND fold bit k of
    // lane into t (t ends as A^(16*lane) * seed). One matrix chain total.
    float s0 = yp1, s1 = yp2;
    float m00 = -c1, m01 = -c2, m10 = 1.f, m11 = 0.f;
    #pragma unroll
    for (int k = 0; k < 4; ++k) SQMAT(m00,m01,m10,m11)   // A -> A^16
    #pragma unroll
    for (int k = 0; k < 6; ++k) {
        int off = 1 << k;
        float p0 = __shfl_up(s0, off, 64);
        float p1 = __shfl_up(s1, off, 64);
        if (lane < off) { p0 = 0.f; p1 = 0.f; }
        s0 += m00*p0 + m01*p1;
        s1 += m10*p0 + m11*p1;
        if (lane & off) {                 // fused seed-expansion (saves e-chain)
            float q0 = m00*t0 + m01*t1;
            float q1 = m10*t0 + m11*t1;
            t0 = q0; t1 = q1;
        }
        SQMAT(m00,m01,m10,m11)
    }

    // exclusive within-wave part
    float ex0 = __shfl_up(s0, 1, 64);
    float ex1 = __shfl_up(s1, 1, 64);
    if (lane == 0) { ex0 = 0.f; ex1 = 0.f; }

    // ---- pass 2: true seed; y overwrites u[] ----
    yp1 = ex0 + t0;
    yp2 = ex1 + t1;
    #pragma unroll
    for (int j = 0; j < CHUNK; ++j) {
        float yj = u[j] - c1*yp1 - c2*yp2;
        yp2 = yp1; yp1 = yj;
        u[j] = yj;
    }

    // ---- transposed non-temporal store (wave-local sync only) ----
    float* wb = &tbuf[wave][0][0];
    #pragma unroll
    for (int q = 0; q < 4; ++q)
        *(float4*)(wb + lane*TP + 4*q) = make_float4(u[4*q], u[4*q+1], u[4*q+2], u[4*q+3]);
    asm volatile("s_waitcnt lgkmcnt(0)" ::: "memory");
    __builtin_amdgcn_sched_barrier(0);
    __builtin_amdgcn_wave_barrier();

    #pragma unroll
    for (int i = 0; i < 4; ++i) {
        int idx = i * 256 + 4 * lane;      // contiguous 1024-float wave run
        int cc  = idx >> 4;                // source thread
        int jj  = idx & 15;                // element within its chunk
        vfloat4 o;
        o.x = wb[cc*TP + jj + 0];
        o.y = wb[cc*TP + jj + 1];
        o.z = wb[cc*TP + jj + 2];
        o.w = wb[cc*TP + jj + 3];
        __builtin_nontemporal_store(o, (vfloat4*)(y + segbase + idx));
    }
}

extern "C" void kernel_launch(void* const* d_in, const int* in_sizes, int n_in,
                              void* d_out, int out_size, void* d_ws, size_t ws_size,
                              hipStream_t stream) {
    const float* x = (const float*)d_in[0];
    const float* b = (const float*)d_in[1];
    const float* a = (const float*)d_in[2];
    float* y = (float*)d_out;

    const int nblocks = in_sizes[0] / (NWAVE * WSEG);   // 8192
    iir_wave_kernel<<<nblocks, NT, 0, stream>>>(x, b, a, y);
}

// Round 14
// 46.268 us; speedup vs baseline: 1.2960x; 1.0161x over previous
//
#include <hip/hip_runtime.h>

#define T_LEN 65536
#define WSEG  1024      // elements per wave segment
#define CHUNK 16        // per-thread elements
#define WARM  24        // seed warm-up: rho^24 = (a2/a0)^12 ~ 6.5e-10, below fp32 eps
#define NT    256       // 4 waves per block
#define NWAVE 4
#define TP    20        // LDS row stride (floats): 16 + 4 pad, 16B-aligned

typedef float vfloat4 __attribute__((ext_vector_type(4)));

#define SQMAT(a00,a01,a10,a11) {                      \
    float n00=a00*a00+a01*a10, n01=a00*a01+a01*a11;   \
    float n10=a10*a00+a11*a10, n11=a10*a01+a11*a11;   \
    a00=n00; a01=n01; a10=n10; a11=n11; }

__attribute__((amdgpu_flat_work_group_size(NT, NT)))
__global__ void iir_wave_kernel(const float* __restrict__ x,
                                const float* __restrict__ bco,
                                const float* __restrict__ aco,
                                float* __restrict__ y)
{
    const int tid  = threadIdx.x;
    const int wave = tid >> 6;
    const int lane = tid & 63;
    const long segbase = (long)blockIdx.x * (NWAVE * WSEG) + (long)wave * WSEG;
    const long base    = segbase + (long)lane * CHUNK;
    const bool rowstart = ((segbase & (T_LEN - 1)) == 0);

    const float inv_a0 = 1.0f / aco[0];
    const float b0 = bco[0]*inv_a0, b1 = bco[1]*inv_a0, b2 = bco[2]*inv_a0;
    const float c1 = aco[1]*inv_a0, c2 = aco[2]*inv_a0;

    __shared__ float tbuf[NWAVE][64][TP];   // 20 KB -> 8 blocks/CU

    // ---- warm-up loads FIRST (they gate pass-1 start via lane0 boundary) ----
    float4 wv0, wv1, wv2, wv3, wv4, wv5;
    if (!rowstart) {
        const float4* wv = (const float4*)(x + segbase - WARM);
        wv0 = wv[0]; wv1 = wv[1]; wv2 = wv[2];
        wv3 = wv[3]; wv4 = wv[4]; wv5 = wv[5];
    }

    // ---- payload loads: 16 floats per lane, in flight under warm-up compute ----
    const float4* xv = (const float4*)(x + base);
    float4 v0 = xv[0], v1 = xv[1], v2 = xv[2], v3 = xv[3];

    // ---- segment seed: all lanes redundantly run WARM steps (broadcast data).
    //      fm1/fm2 end as x[segbase-1], x[segbase-2] (lane0 FIR boundary);
    //      (t0,t1) = (y[segbase-1], y[segbase-2]) with ~6e-10 truncation error. ----
    float fm1 = 0.f, fm2 = 0.f;
    float t0 = 0.f, t1 = 0.f;
    if (!rowstart) {
        float w1 = 0.f, w2 = 0.f;
        float4 wvv[6] = { wv0, wv1, wv2, wv3, wv4, wv5 };
        #pragma unroll
        for (int q = 0; q < WARM / 4; ++q) {
            float4 v = wvv[q];
            float u0 = b0*v.x + b1*fm1 + b2*fm2;
            float u1 = b0*v.y + b1*v.x + b2*fm1;
            float u2 = b0*v.z + b1*v.y + b2*v.x;
            float u3 = b0*v.w + b1*v.z + b2*v.y;
            fm2 = v.z; fm1 = v.w;
            float y0 = u0 - c1*w1 - c2*w2;
            float y1 = u1 - c1*y0 - c2*w1;
            float y2 = u2 - c1*y1 - c2*y0;
            float y3 = u3 - c1*y2 - c2*y1;
            w2 = y2; w1 = y3;
        }
        t0 = w1; t1 = w2;
    }

    // ---- FIR boundary: neighbor lane's last two x via shuffle ----
    float xm1 = __shfl_up(v3.w, 1, 64);
    float xm2 = __shfl_up(v3.z, 1, 64);
    if (lane == 0) { xm1 = fm1; xm2 = fm2; }   // exact zeros at rowstart

    // ---- FIR + zero-state pass 1 (u kept in registers) ----
    float u[CHUNK];
    float yp1 = 0.f, yp2 = 0.f;
#define STEP4(V, O)                                                  \
    {                                                                \
        float u0 = b0*(V).x + b1*xm1   + b2*xm2;                     \
        float u1 = b0*(V).y + b1*(V).x + b2*xm1;                     \
        float u2 = b0*(V).z + b1*(V).y + b2*(V).x;                   \
        float u3 = b0*(V).w + b1*(V).z + b2*(V).y;                   \
        xm2 = (V).z; xm1 = (V).w;                                    \
        u[(O)+0]=u0; u[(O)+1]=u1; u[(O)+2]=u2; u[(O)+3]=u3;          \
        float y0 = u0 - c1*yp1 - c2*yp2;                             \
        float y1 = u1 - c1*y0  - c2*yp1;                             \
        float y2 = u2 - c1*y1  - c2*y0;                              \
        float y3 = u3 - c1*y2  - c2*y1;                              \
        yp2 = y2; yp1 = y3;                                          \
    }
    STEP4(v0, 0) STEP4(v1, 4) STEP4(v2, 8) STEP4(v3, 12)
#undef STEP4
    #pragma unroll
    for (int j = 0; j < CHUNK; ++j) asm volatile("" : "+v"(u[j]));  // no remat

    // ---- intra-wave inclusive scan + fused seed transform ----
    // At scan step k, m = A^(16*2^k): combine partials AND fold bit k of
    // lane into t (t ends as A^(16*lane) * seed). One matrix chain total.
    float s0 = yp1, s1 = yp2;
    float m00 = -c1, m01 = -c2, m10 = 1.f, m11 = 0.f;
    #pragma unroll
    for (int k = 0; k < 4; ++k) SQMAT(m00,m01,m10,m11)   // A -> A^16
    #pragma unroll
    for (int k = 0; k < 6; ++k) {
        int off = 1 << k;
        float p0 = __shfl_up(s0, off, 64);
        float p1 = __shfl_up(s1, off, 64);
        if (lane < off) { p0 = 0.f; p1 = 0.f; }
        s0 += m00*p0 + m01*p1;
        s1 += m10*p0 + m11*p1;
        if (lane & off) {                 // fused seed-expansion
            float q0 = m00*t0 + m01*t1;
            float q1 = m10*t0 + m11*t1;
            t0 = q0; t1 = q1;
        }
        SQMAT(m00,m01,m10,m11)
    }

    // exclusive within-wave part
    float ex0 = __shfl_up(s0, 1, 64);
    float ex1 = __shfl_up(s1, 1, 64);
    if (lane == 0) { ex0 = 0.f; ex1 = 0.f; }

    // ---- pass 2: true seed; y overwrites u[] ----
    yp1 = ex0 + t0;
    yp2 = ex1 + t1;
    #pragma unroll
    for (int j = 0; j < CHUNK; ++j) {
        float yj = u[j] - c1*yp1 - c2*yp2;
        yp2 = yp1; yp1 = yj;
        u[j] = yj;
    }

    // ---- transposed non-temporal store (wave-local sync only).
    //      NOTE: __builtin_nontemporal_store (nt bit only) is the max safe
    //      policy here: sc0/sc1 L2-bypass broke coherence with the harness's
    //      memset-then-validate path (R13). ----
    float* wb = &tbuf[wave][0][0];
    #pragma unroll
    for (int q = 0; q < 4; ++q)
        *(float4*)(wb + lane*TP + 4*q) = make_float4(u[4*q], u[4*q+1], u[4*q+2], u[4*q+3]);
    asm volatile("s_waitcnt lgkmcnt(0)" ::: "memory");
    __builtin_amdgcn_sched_barrier(0);
    __builtin_amdgcn_wave_barrier();

    #pragma unroll
    for (int i = 0; i < 4; ++i) {
        int idx = i * 256 + 4 * lane;      // contiguous 1024-float wave run
        int cc  = idx >> 4;                // source thread
        int jj  = idx & 15;                // element within its chunk
        vfloat4 o;
        o.x = wb[cc*TP + jj + 0];
        o.y = wb[cc*TP + jj + 1];
        o.z = wb[cc*TP + jj + 2];
        o.w = wb[cc*TP + jj + 3];
        __builtin_nontemporal_store(o, (vfloat4*)(y + segbase + idx));
    }
}

extern "C" void kernel_launch(void* const* d_in, const int* in_sizes, int n_in,
                              void* d_out, int out_size, void* d_ws, size_t ws_size,
                              hipStream_t stream) {
    const float* x = (const float*)d_in[0];
    const float* b = (const float*)d_in[1];
    const float* a = (const float*)d_in[2];
    float* y = (float*)d_out;

    const int nblocks = in_sizes[0] / (NWAVE * WSEG);   // 8192
    iir_wave_kernel<<<nblocks, NT, 0, stream>>>(x, b, a, y);
}

// Round 15
// 44.567 us; speedup vs baseline: 1.3455x; 1.0382x over previous
//
#include <hip/hip_runtime.h>

#define T_LEN 65536
#define WSEG  1024      // elements per segment
#define NSEG  4         // consecutive segments per wave (exact carry between them)
#define CHUNK 16        // per-thread elements per segment
#define WARM  24        // first-segment seed warm-up: rho^24 ~ 6.5e-10
#define NT    256       // 4 waves per block
#define NWAVE 4
#define TP    20        // LDS row stride (floats): 16 + 4 pad

typedef float vfloat4 __attribute__((ext_vector_type(4)));

#define SQMAT(a00,a01,a10,a11) {                      \
    float n00=a00*a00+a01*a10, n01=a00*a01+a01*a11;   \
    float n10=a10*a00+a11*a10, n11=a10*a01+a11*a11;   \
    a00=n00; a01=n01; a10=n10; a11=n11; }

#define WAVE_FENCE() do {                                   \
    asm volatile("s_waitcnt lgkmcnt(0)" ::: "memory");      \
    __builtin_amdgcn_sched_barrier(0);                      \
    __builtin_amdgcn_wave_barrier();                        \
} while (0)

__attribute__((amdgpu_flat_work_group_size(NT, NT)))
__global__ void iir_wave_kernel(const float* __restrict__ x,
                                const float* __restrict__ bco,
                                const float* __restrict__ aco,
                                float* __restrict__ y)
{
    const int tid  = threadIdx.x;
    const int wave = tid >> 6;
    const int lane = tid & 63;
    // wave owns NSEG consecutive segments (never crosses a row: 65536 % 4096 == 0)
    const long wbase = (long)blockIdx.x * (NWAVE * NSEG * WSEG) + (long)wave * (NSEG * WSEG);
    const bool rowstart = ((wbase & (T_LEN - 1)) == 0);

    const float inv_a0 = 1.0f / aco[0];
    const float b0 = bco[0]*inv_a0, b1 = bco[1]*inv_a0, b2 = bco[2]*inv_a0;
    const float c1 = aco[1]*inv_a0, c2 = aco[2]*inv_a0;

    __shared__ float tbuf[NWAVE][64][TP];   // 20 KB

    // ---- warm-up loads first (gate the first segment's seed) ----
    float4 wv0, wv1, wv2, wv3, wv4, wv5;
    if (!rowstart) {
        const float4* wv = (const float4*)(x + wbase - WARM);
        wv0 = wv[0]; wv1 = wv[1]; wv2 = wv[2];
        wv3 = wv[3]; wv4 = wv[4]; wv5 = wv[5];
    }

    // ---- segment-0 payload loads (in flight under warm-up compute) ----
    const float4* xv = (const float4*)(x + wbase + (long)lane * CHUNK);
    float4 a0 = xv[0], a1 = xv[1], a2 = xv[2], a3 = xv[3];

    // ---- first-segment seed: all lanes redundantly run WARM steps ----
    float fm1 = 0.f, fm2 = 0.f;   // x[segstart-1], x[segstart-2]
    float t0 = 0.f, t1 = 0.f;     // y[segstart-1], y[segstart-2]
    if (!rowstart) {
        float w1 = 0.f, w2 = 0.f;
        float4 wvv[6] = { wv0, wv1, wv2, wv3, wv4, wv5 };
        #pragma unroll
        for (int q = 0; q < WARM / 4; ++q) {
            float4 v = wvv[q];
            float u0 = b0*v.x + b1*fm1 + b2*fm2;
            float u1 = b0*v.y + b1*v.x + b2*fm1;
            float u2 = b0*v.z + b1*v.y + b2*v.x;
            float u3 = b0*v.w + b1*v.z + b2*v.y;
            fm2 = v.z; fm1 = v.w;
            float y0 = u0 - c1*w1 - c2*w2;
            float y1 = u1 - c1*y0 - c2*w1;
            float y2 = u2 - c1*y1 - c2*y0;
            float y3 = u3 - c1*y2 - c2*y1;
            w2 = y2; w1 = y3;
        }
        t0 = w1; t1 = w2;
    }

    float* wb = &tbuf[wave][0][0];

    #pragma unroll
    for (int s = 0; s < NSEG; ++s) {
        const long segbase = wbase + (long)s * WSEG;

        // ---- prefetch next segment's payload (in flight under this segment) ----
        float4 nb0, nb1, nb2, nb3;
        if (s < NSEG - 1) {
            const float4* nx = (const float4*)(x + segbase + WSEG + (long)lane * CHUNK);
            nb0 = nx[0]; nb1 = nx[1]; nb2 = nx[2]; nb3 = nx[3];
        }

        // ---- FIR boundary: neighbor lane's last two x via shuffle ----
        float xm1 = __shfl_up(a3.w, 1, 64);
        float xm2 = __shfl_up(a3.z, 1, 64);
        if (lane == 0) { xm1 = fm1; xm2 = fm2; }

        // ---- FIR + zero-state pass 1 (u kept in registers) ----
        float u[CHUNK];
        float yp1 = 0.f, yp2 = 0.f;
#define STEP4(V, O)                                                  \
        {                                                            \
            float u0 = b0*(V).x + b1*xm1   + b2*xm2;                 \
            float u1 = b0*(V).y + b1*(V).x + b2*xm1;                 \
            float u2 = b0*(V).z + b1*(V).y + b2*(V).x;               \
            float u3 = b0*(V).w + b1*(V).z + b2*(V).y;               \
            xm2 = (V).z; xm1 = (V).w;                                \
            u[(O)+0]=u0; u[(O)+1]=u1; u[(O)+2]=u2; u[(O)+3]=u3;      \
            float y0 = u0 - c1*yp1 - c2*yp2;                         \
            float y1 = u1 - c1*y0  - c2*yp1;                         \
            float y2 = u2 - c1*y1  - c2*y0;                          \
            float y3 = u3 - c1*y2  - c2*y1;                          \
            yp2 = y2; yp1 = y3;                                      \
        }
        STEP4(a0, 0) STEP4(a1, 4) STEP4(a2, 8) STEP4(a3, 12)
#undef STEP4
        #pragma unroll
        for (int j = 0; j < CHUNK; ++j) asm volatile("" : "+v"(u[j]));  // no remat

        // ---- intra-wave scan + fused seed transform (one matrix chain) ----
        float s0 = yp1, s1 = yp2;
        float m00 = -c1, m01 = -c2, m10 = 1.f, m11 = 0.f;
        #pragma unroll
        for (int k = 0; k < 4; ++k) SQMAT(m00,m01,m10,m11)   // A -> A^16
        #pragma unroll
        for (int k = 0; k < 6; ++k) {
            int off = 1 << k;
            float p0 = __shfl_up(s0, off, 64);
            float p1 = __shfl_up(s1, off, 64);
            if (lane < off) { p0 = 0.f; p1 = 0.f; }
            s0 += m00*p0 + m01*p1;
            s1 += m10*p0 + m11*p1;
            if (lane & off) {                 // t -> A^(16*lane) * seed
                float q0 = m00*t0 + m01*t1;
                float q1 = m10*t0 + m11*t1;
                t0 = q0; t1 = q1;
            }
            SQMAT(m00,m01,m10,m11)
        }

        // exclusive within-wave part
        float ex0 = __shfl_up(s0, 1, 64);
        float ex1 = __shfl_up(s1, 1, 64);
        if (lane == 0) { ex0 = 0.f; ex1 = 0.f; }

        // ---- pass 2: true seed; y overwrites u[] ----
        yp1 = ex0 + t0;
        yp2 = ex1 + t1;
        #pragma unroll
        for (int j = 0; j < CHUNK; ++j) {
            float yj = u[j] - c1*yp1 - c2*yp2;
            yp2 = yp1; yp1 = yj;
            u[j] = yj;
        }

        // ---- EXACT carry to next segment: lane 63 end state + last x ----
        float ct0 = __shfl(yp1, 63, 64);    // y[segend-1]
        float ct1 = __shfl(yp2, 63, 64);    // y[segend-2]
        float cf1 = __shfl(a3.w, 63, 64);   // x[segend-1]
        float cf2 = __shfl(a3.z, 63, 64);   // x[segend-2]

        // ---- transposed non-temporal store (wave-local sync only) ----
        #pragma unroll
        for (int q = 0; q < 4; ++q)
            *(float4*)(wb + lane*TP + 4*q) = make_float4(u[4*q], u[4*q+1], u[4*q+2], u[4*q+3]);
        WAVE_FENCE();
        #pragma unroll
        for (int i = 0; i < 4; ++i) {
            int idx = i * 256 + 4 * lane;      // contiguous 1024-float wave run
            int cc  = idx >> 4;
            int jj  = idx & 15;
            vfloat4 o;
            o.x = wb[cc*TP + jj + 0];
            o.y = wb[cc*TP + jj + 1];
            o.z = wb[cc*TP + jj + 2];
            o.w = wb[cc*TP + jj + 3];
            __builtin_nontemporal_store(o, (vfloat4*)(y + segbase + idx));
        }
        WAVE_FENCE();   // LDS reads done before next segment overwrites tbuf

        // rotate state
        t0 = ct0; t1 = ct1; fm1 = cf1; fm2 = cf2;
        a0 = nb0; a1 = nb1; a2 = nb2; a3 = nb3;
    }
}

extern "C" void kernel_launch(void* const* d_in, const int* in_sizes, int n_in,
                              void* d_out, int out_size, void* d_ws, size_t ws_size,
                              hipStream_t stream) {
    const float* x = (const float*)d_in[0];
    const float* b = (const float*)d_in[1];
    const float* a = (const float*)d_in[2];
    float* y = (float*)d_out;

    const int nblocks = in_sizes[0] / (NWAVE * NSEG * WSEG);   // 2048
    iir_wave_kernel<<<nblocks, NT, 0, stream>>>(x, b, a, y);
}